// Round 1
// baseline (11.607 us; speedup 1.0000x reference)
//
#include <hip/hip_runtime.h>

// Problem constants (from reference): N=2048, M=512, F=256.
// out[n,m] = sum_f (note[n,f]-lab[m,f])*W[f] + b
//          = dot(note[n],W) - dot(lab[m],W) + b   (exact factorization)

#define N_ROWS 2048
#define M_ROWS 512
#define FDIM   256

// Kernel 1: one 64-lane wave per row; lane i handles floats [4i, 4i+4).
// Rows 0..N-1 -> noteFea dots, rows N..N+M-1 -> labFea dots.
__global__ void siamese_dots(const float* __restrict__ note,
                             const float* __restrict__ lab,
                             const float* __restrict__ W,
                             float* __restrict__ ws) {
    int gid  = blockIdx.x * blockDim.x + threadIdx.x;
    int wave = gid >> 6;          // global wave index
    int lane = threadIdx.x & 63;
    const int total = N_ROWS + M_ROWS;
    if (wave >= total) return;

    const float* row = (wave < N_ROWS)
        ? note + (size_t)wave * FDIM
        : lab  + (size_t)(wave - N_ROWS) * FDIM;

    float4 v = reinterpret_cast<const float4*>(row)[lane];
    float4 w = reinterpret_cast<const float4*>(W)[lane];
    float s = v.x * w.x + v.y * w.y + v.z * w.z + v.w * w.w;

    // 64-lane butterfly reduce
    #pragma unroll
    for (int off = 32; off > 0; off >>= 1)
        s += __shfl_down(s, off, 64);

    if (lane == 0) ws[wave] = s;
}

// Kernel 2: out[n,m] = a[n] - c[m] + b, vectorized float4 over m.
// M/4 = 128 float4 per row; total N * 128 = 262144 threads.
__global__ void siamese_fill(const float* __restrict__ ws,
                             const float* __restrict__ bptr,
                             float* __restrict__ out) {
    int idx = blockIdx.x * blockDim.x + threadIdx.x;   // one float4 each
    int mq  = idx & (M_ROWS / 4 - 1);                  // 0..127
    int n   = idx >> 7;                                // 0..2047

    float a  = ws[n];
    float4 c = reinterpret_cast<const float4*>(ws + N_ROWS)[mq];
    float bb = bptr[0];

    float4 o;
    o.x = a - c.x + bb;
    o.y = a - c.y + bb;
    o.z = a - c.z + bb;
    o.w = a - c.w + bb;
    reinterpret_cast<float4*>(out)[idx] = o;
}

extern "C" void kernel_launch(void* const* d_in, const int* in_sizes, int n_in,
                              void* d_out, int out_size, void* d_ws, size_t ws_size,
                              hipStream_t stream) {
    const float* note = (const float*)d_in[0];   // [N, F]
    const float* lab  = (const float*)d_in[1];   // [M, F]
    const float* W    = (const float*)d_in[2];   // [F]
    const float* b    = (const float*)d_in[3];   // [1]
    float* out        = (float*)d_out;           // [N, M]
    float* ws         = (float*)d_ws;            // N + M floats of scratch

    // Kernel 1: (N+M) waves = 2560 waves; 4 waves per 256-thread block -> 640 blocks
    {
        const int total_waves = N_ROWS + M_ROWS;
        const int block = 256;
        const int waves_per_block = block / 64;
        const int grid = (total_waves + waves_per_block - 1) / waves_per_block;
        siamese_dots<<<grid, block, 0, stream>>>(note, lab, W, ws);
    }

    // Kernel 2: N*M/4 float4 stores = 262144 threads -> 1024 blocks of 256
    {
        const int total = N_ROWS * (M_ROWS / 4);
        const int block = 256;
        const int grid = total / block;
        siamese_fill<<<grid, block, 0, stream>>>(ws, b, out);
    }
}